// Round 11
// baseline (402.294 us; speedup 1.0000x reference)
//
#include <hip/hip_runtime.h>
#include <hip/hip_bf16.h>

typedef float f32x4 __attribute__((ext_vector_type(4)));
typedef short short8 __attribute__((ext_vector_type(8)));
typedef unsigned short u16;
typedef unsigned int u32;
typedef unsigned int u32x4 __attribute__((ext_vector_type(4)));

#define NEG_MAX (-3.4028234663852886e38f)
#define NODE_SCALE 0.125f
#define EDGE_SCALE 0.70710678118654752f
#define TSTR 68   // f32 per E-tile row
#define PSTR 36   // f32 per P row (A cols 0-15, B cols 16-31)
#define WREG 2496 // per-wave LDS floats: tA(1088)+tB(1088)+Pf(288)+Rg(8)+pad

__device__ __forceinline__ u16 f2bf(float f) {
  unsigned int x = __builtin_bit_cast(unsigned int, f);
  x = x + 0x7FFFu + ((x >> 16) & 1u);
  return (u16)(x >> 16);
}
__device__ __forceinline__ float asf(u32 x) { return __builtin_bit_cast(float, x); }
__device__ __forceinline__ u32 cvtpk(float lo, float hi) {
  u32 r;
  asm("v_cvt_pk_bf16_f32 %0, %1, %2" : "=v"(r) : "v"(lo), "v"(hi));
  return r;
}

// ---------------- kernel M: normalize mask to float 0/1 (dtype-robust) ----
__global__ void mask_norm(const unsigned char* __restrict__ mraw,
                          float* __restrict__ mask_f) {
  __shared__ int flags;
  int t = threadIdx.x;
  if (t == 0) flags = 0;
  __syncthreads();
  const unsigned int* mu = (const unsigned int*)mraw;
  int f = 0;
  for (int e = t; e < 512; e += 256) { if (mu[e] > 1u) f |= 1; }
  for (int e = t; e < 2048; e += 256) { if (mraw[e] > 1) f |= 2; }
  if (f) atomicOr(&flags, f);
  __syncthreads();
  int fl = flags;
  for (int e = t; e < 2048; e += 256) {
    float v;
    if (!(fl & 1))      v = (mu[e] != 0u) ? 1.f : 0.f;
    else if (!(fl & 2)) v = (mraw[e] != 0) ? 1.f : 0.f;
    else                v = (((const float*)mraw)[e] != 0.f) ? 1.f : 0.f;
    mask_f[e] = v;
  }
}

// ---------------- kernel A: qkv projection + rotary ----------------------
__global__ __launch_bounds__(256) void qkv_rope(
    const float* __restrict__ node, const float* __restrict__ Wq,
    const float* __restrict__ Wk, const float* __restrict__ Wv,
    float* __restrict__ qw, u16* __restrict__ kwb, u16* __restrict__ vwb) {
  __shared__ __align__(16) float xs[8 * 256];
  int t = threadIdx.x;
  int row0 = blockIdx.x * 8;
#pragma unroll
  for (int p = 0; p < 2; ++p) {
    int f = p * 256 + t;
    *(f32x4*)(&xs[f * 4]) = *(const f32x4*)(node + (size_t)row0 * 256 + f * 4);
  }
  __syncthreads();
  float qa[8], ka[8], va[8];
#pragma unroll
  for (int r = 0; r < 8; ++r) { qa[r] = 0.f; ka[r] = 0.f; va[r] = 0.f; }
  for (int c = 0; c < 256; ++c) {
    float wq = Wq[c * 256 + t];
    float wk = Wk[c * 256 + t];
    float wv = Wv[c * 256 + t];
#pragma unroll
    for (int r = 0; r < 8; ++r) {
      float x = xs[r * 256 + c];
      qa[r] += x * wq; ka[r] += x * wk; va[r] += x * wv;
    }
  }
  int d = t & 31;
  float inv = powf(10000.f, -((float)(2 * (d >> 1)) * (1.f / 32.f)));
  int h = t >> 5;
#pragma unroll
  for (int r = 0; r < 8; ++r) {
    int gr = row0 + r;
    int b = gr >> 10, i = gr & 1023;
    float ang = (float)i * inv;
    float sn, cs;
    sincosf(ang, &sn, &cs);
    float qp = __shfl_xor(qa[r], 1, 64);
    float kp = __shfl_xor(ka[r], 1, 64);
    float qo = (d & 1) ? (qp * sn + qa[r] * cs) : (qa[r] * cs - qp * sn);
    float ko = (d & 1) ? (kp * sn + ka[r] * cs) : (ka[r] * cs - kp * sn);
    int idx = ((b * 8 + h) * 1024 + i) * 32 + d;
    qw[idx] = qo;
    kwb[idx] = f2bf(ko);
    vwb[idx] = f2bf(va[r]);
  }
}

// ---------------- kernel B: fused attention, 2-tile ILP, barrier-free ----
__global__ __launch_bounds__(256) void attn_fused(
    const float* __restrict__ edge, const float* __restrict__ qw,
    const u16* __restrict__ kwb, const u16* __restrict__ vwb,
    const float* __restrict__ We, const float* __restrict__ be,
    const float* __restrict__ mask_f, float* __restrict__ rescat) {
  __shared__ __align__(16) float S[4 * WREG];  // 39.9 KB; epilogue reuses as MRG

  int bid = blockIdx.x;
  int xcd = bid & 7, slot = bid >> 3;
  int b = xcd >> 2;
  int i = (xcd & 3) * 256 + slot;
  int t = threadIdx.x;
  int lane = t & 63;
  int w = __builtin_amdgcn_readfirstlane(t >> 6);

  float* base = S + w * WREG;
  float* tA = base;
  float* tB = base + 1088;
  float* Pf = base + 2176;
  float* Rg = base + 2464;

  int j16 = lane & 15;
  int hq = lane >> 4;
  int hD = lane >> 3, sD = lane & 7;
  int jrl = lane >> 2, c4 = lane & 3;
  int jh = sD >> 2, do4 = sD & 3;

  // ---- prologue ----------------------------------------------------------
  float mi = mask_f[b * 1024 + i];
  u32 mb = 0;
  if (mi != 0.f) {
#pragma unroll
    for (int tt = 0; tt < 16; ++tt) {
      float v = mask_f[b * 1024 + tt * 64 + w * 16 + j16];
      mb |= (v != 0.f ? 1u : 0u) << tt;
    }
  }
  f32x4 besq = *(const f32x4*)(be + (hq & 1) * 4);
  besq *= EDGE_SCALE;

  short8 weA0, weA1;
  {
    int hh = lane & 15, g = lane >> 4;
#pragma unroll
    for (int e = 0; e < 8; ++e) {
      int d0 = g * 8 + e;
      float w0 = (hh < 8) ? We[d0 * 8 + hh] * EDGE_SCALE : 0.f;
      float w1 = (hh < 8) ? We[(d0 + 32) * 8 + hh] * EDGE_SCALE : 0.f;
      weA0[e] = (short)f2bf(w0);
      weA1[e] = (short)f2bf(w1);
    }
  }

  // q A-fragments: block-diagonal (step h has only row h nonzero), built once
  short8 qA[8];
  {
    int hh = (lane & 15) & 7;
    const float* qp = qw + ((size_t)((b * 8 + hh) * 1024 + i)) * 32 + (lane >> 4) * 8;
    f32x4 qv0 = *(const f32x4*)(qp);
    f32x4 qv1 = *(const f32x4*)(qp + 4);
    qv0 *= NODE_SCALE;
    qv1 *= NODE_SCALE;
    u32x4 qpk;
    qpk[0] = cvtpk(qv0.x, qv0.y); qpk[1] = cvtpk(qv0.z, qv0.w);
    qpk[2] = cvtpk(qv1.x, qv1.y); qpk[3] = cvtpk(qv1.z, qv1.w);
    u32x4 zz = {0u, 0u, 0u, 0u};
#pragma unroll
    for (int h = 0; h < 8; ++h)
      qA[h] = __builtin_bit_cast(short8, ((lane & 15) == h) ? qpk : zz);
  }

  const float* ebase = edge + ((size_t)(b * 1024 + i)) * (1024 * 64);
  const float* gsrc = ebase + (size_t)(w * 16 + jrl) * 64 + c4 * 16;

  // stage tiles 0 -> tA and 1 -> tB (wave-local; no barrier in loop)
  {
    f32x4 a0 = __builtin_nontemporal_load((const f32x4*)(gsrc + 0));
    f32x4 a1 = __builtin_nontemporal_load((const f32x4*)(gsrc + 4));
    f32x4 a2 = __builtin_nontemporal_load((const f32x4*)(gsrc + 8));
    f32x4 a3 = __builtin_nontemporal_load((const f32x4*)(gsrc + 12));
    const float* g2 = gsrc + 64 * 64;
    f32x4 b0 = __builtin_nontemporal_load((const f32x4*)(g2 + 0));
    f32x4 b1 = __builtin_nontemporal_load((const f32x4*)(g2 + 4));
    f32x4 b2 = __builtin_nontemporal_load((const f32x4*)(g2 + 8));
    f32x4 b3 = __builtin_nontemporal_load((const f32x4*)(g2 + 12));
    float* wa = tA + jrl * TSTR + c4 * 16;
    float* wb = tB + jrl * TSTR + c4 * 16;
    *(f32x4*)(wa + 0) = a0; *(f32x4*)(wa + 4) = a1;
    *(f32x4*)(wa + 8) = a2; *(f32x4*)(wa + 12) = a3;
    *(f32x4*)(wb + 0) = b0; *(f32x4*)(wb + 4) = b1;
    *(f32x4*)(wb + 8) = b2; *(f32x4*)(wb + 12) = b3;
  }

  f32x4 vm = {NEG_MAX, NEG_MAX, NEG_MAX, NEG_MAX};
  f32x4 vs = {0.f, 0.f, 0.f, 0.f};
  f32x4 av0 = {0.f, 0.f, 0.f, 0.f}, av1 = {0.f, 0.f, 0.f, 0.f};
  f32x4 acce0 = {0.f, 0.f, 0.f, 0.f}, acce1 = {0.f, 0.f, 0.f, 0.f};
  f32x4 acce2 = {0.f, 0.f, 0.f, 0.f}, acce3 = {0.f, 0.f, 0.f, 0.f};

  for (int m = 0; m < 8; ++m) {
    int j0 = m * 128;
    bool pf = m < 7;
    f32x4 sA0, sA1, sA2, sA3, sB0, sB1, sB2, sB3;
    if (pf) {
      const float* gA = gsrc + (size_t)(j0 + 128) * 64;
      const float* gB = gsrc + (size_t)(j0 + 192) * 64;
      sA0 = __builtin_nontemporal_load((const f32x4*)(gA + 0));
      sA1 = __builtin_nontemporal_load((const f32x4*)(gA + 4));
      sA2 = __builtin_nontemporal_load((const f32x4*)(gA + 8));
      sA3 = __builtin_nontemporal_load((const f32x4*)(gA + 12));
      sB0 = __builtin_nontemporal_load((const f32x4*)(gB + 0));
      sB1 = __builtin_nontemporal_load((const f32x4*)(gB + 4));
      sB2 = __builtin_nontemporal_load((const f32x4*)(gB + 8));
      sB3 = __builtin_nontemporal_load((const f32x4*)(gB + 12));
    }

    // ---- logits tile A: K loads + 2 bias MFMAs + 8 block-diag QK MFMAs ---
    short8 kA[8];
#pragma unroll
    for (int h = 0; h < 8; ++h)
      kA[h] = *(const short8*)(kwb +
          ((size_t)((b * 8 + h) * 1024 + j0 + w * 16 + j16)) * 32 + hq * 8);
    f32x4 baccA = {0.f, 0.f, 0.f, 0.f};
    {
      const float* rp = tA + j16 * TSTR + hq * 8;
      f32x4 ea0 = *(const f32x4*)(rp + 0);
      f32x4 ea1 = *(const f32x4*)(rp + 4);
      f32x4 eb0 = *(const f32x4*)(rp + 32);
      f32x4 eb1 = *(const f32x4*)(rp + 36);
      u32x4 p0, p1;
      p0[0] = cvtpk(ea0.x, ea0.y); p0[1] = cvtpk(ea0.z, ea0.w);
      p0[2] = cvtpk(ea1.x, ea1.y); p0[3] = cvtpk(ea1.z, ea1.w);
      p1[0] = cvtpk(eb0.x, eb0.y); p1[1] = cvtpk(eb0.z, eb0.w);
      p1[2] = cvtpk(eb1.x, eb1.y); p1[3] = cvtpk(eb1.z, eb1.w);
      baccA = __builtin_amdgcn_mfma_f32_16x16x32_bf16(
          weA0, __builtin_bit_cast(short8, p0), baccA, 0, 0, 0);
      baccA = __builtin_amdgcn_mfma_f32_16x16x32_bf16(
          weA1, __builtin_bit_cast(short8, p1), baccA, 0, 0, 0);
    }
#pragma unroll
    for (int h = 0; h < 8; ++h)
      baccA = __builtin_amdgcn_mfma_f32_16x16x32_bf16(qA[h], kA[h], baccA, 0, 0, 0);

    // ---- logits tile B ----------------------------------------------------
    short8 kB[8];
#pragma unroll
    for (int h = 0; h < 8; ++h)
      kB[h] = *(const short8*)(kwb +
          ((size_t)((b * 8 + h) * 1024 + j0 + 64 + w * 16 + j16)) * 32 + hq * 8);
    f32x4 baccB = {0.f, 0.f, 0.f, 0.f};
    {
      const float* rp = tB + j16 * TSTR + hq * 8;
      f32x4 ea0 = *(const f32x4*)(rp + 0);
      f32x4 ea1 = *(const f32x4*)(rp + 4);
      f32x4 eb0 = *(const f32x4*)(rp + 32);
      f32x4 eb1 = *(const f32x4*)(rp + 36);
      u32x4 p0, p1;
      p0[0] = cvtpk(ea0.x, ea0.y); p0[1] = cvtpk(ea0.z, ea0.w);
      p0[2] = cvtpk(ea1.x, ea1.y); p0[3] = cvtpk(ea1.z, ea1.w);
      p1[0] = cvtpk(eb0.x, eb0.y); p1[1] = cvtpk(eb0.z, eb0.w);
      p1[2] = cvtpk(eb1.x, eb1.y); p1[3] = cvtpk(eb1.z, eb1.w);
      baccB = __builtin_amdgcn_mfma_f32_16x16x32_bf16(
          weA0, __builtin_bit_cast(short8, p0), baccB, 0, 0, 0);
      baccB = __builtin_amdgcn_mfma_f32_16x16x32_bf16(
          weA1, __builtin_bit_cast(short8, p1), baccB, 0, 0, 0);
    }
#pragma unroll
    for (int h = 0; h < 8; ++h)
      baccB = __builtin_amdgcn_mfma_f32_16x16x32_bf16(qA[h], kB[h], baccB, 0, 0, 0);

    // ---- joint online softmax over 128 j ---------------------------------
    {
      bool pmA = (mb >> (2 * m)) & 1u;
      bool pmB = (mb >> (2 * m + 1)) & 1u;
      f32x4 lA, lB, pA, pB, mx;
#pragma unroll
      for (int r = 0; r < 4; ++r) {
        lA[r] = pmA ? (baccA[r] + besq[r]) : NEG_MAX;
        lB[r] = pmB ? (baccB[r] + besq[r]) : NEG_MAX;
        mx[r] = fmaxf(lA[r], lB[r]);
      }
#pragma unroll
      for (int off = 1; off < 16; off <<= 1) {
#pragma unroll
        for (int r = 0; r < 4; ++r) mx[r] = fmaxf(mx[r], __shfl_xor(mx[r], off, 64));
      }
      f32x4 mn, rs, ps;
#pragma unroll
      for (int r = 0; r < 4; ++r) {
        mn[r] = fmaxf(vm[r], mx[r]);
        pA[r] = __expf(lA[r] - mn[r]);
        pB[r] = __expf(lB[r] - mn[r]);
        ps[r] = pA[r] + pB[r];
      }
#pragma unroll
      for (int off = 1; off < 16; off <<= 1) {
#pragma unroll
        for (int r = 0; r < 4; ++r) ps[r] += __shfl_xor(ps[r], off, 64);
      }
#pragma unroll
      for (int r = 0; r < 4; ++r) rs[r] = __expf(vm[r] - mn[r]);
      vs = vs * rs + ps;
      vm = mn;
      if (lane < 32) {
        float* pw = Pf + hq * (4 * PSTR) + j16;
        pw[0 * PSTR] = pA[0]; pw[1 * PSTR] = pA[1];
        pw[2 * PSTR] = pA[2]; pw[3 * PSTR] = pA[3];
        pw[0 * PSTR + 16] = pB[0]; pw[1 * PSTR + 16] = pB[1];
        pw[2 * PSTR + 16] = pB[2]; pw[3 * PSTR + 16] = pB[3];
        if (j16 == 0) *(f32x4*)(Rg + hq * 4) = rs;
      }
    }

    // ---- D1: PV over both tiles (one rescale) -----------------------------
    {
      float r = Rg[hD];
      const float* prow = Pf + hD * PSTR;
      f32x4 a0 = *(const f32x4*)(prow + 0);
      f32x4 a1 = *(const f32x4*)(prow + 4);
      f32x4 a2 = *(const f32x4*)(prow + 8);
      f32x4 a3 = *(const f32x4*)(prow + 12);
      f32x4 b0 = *(const f32x4*)(prow + 16);
      f32x4 b1 = *(const f32x4*)(prow + 20);
      f32x4 b2 = *(const f32x4*)(prow + 24);
      f32x4 b3 = *(const f32x4*)(prow + 28);
      f32x4 prA = jh ? a2 : a0, prA2 = jh ? a3 : a1;
      f32x4 prB = jh ? b2 : b0, prB2 = jh ? b3 : b1;
      const u16* vbA = vwb + ((size_t)((b * 8 + hD) * 1024 + j0 + w * 16 + jh * 8)) * 32 + do4 * 8;
      const u16* vbB = vbA + (size_t)64 * 32;
      f32x4 sv0 = {0.f, 0.f, 0.f, 0.f}, sv1 = {0.f, 0.f, 0.f, 0.f};
#pragma unroll
      for (int x = 0; x < 8; ++x) {
        float pv = (x < 4) ? prA[x] : prA2[x - 4];
        u32x4 vv = *(const u32x4*)(vbA + (size_t)x * 32);
        f32x4 e0 = {asf(vv[0] << 16), asf(vv[0] & 0xffff0000u),
                    asf(vv[1] << 16), asf(vv[1] & 0xffff0000u)};
        f32x4 e1 = {asf(vv[2] << 16), asf(vv[2] & 0xffff0000u),
                    asf(vv[3] << 16), asf(vv[3] & 0xffff0000u)};
        sv0 += e0 * pv;
        sv1 += e1 * pv;
      }
#pragma unroll
      for (int x = 0; x < 8; ++x) {
        float pv = (x < 4) ? prB[x] : prB2[x - 4];
        u32x4 vv = *(const u32x4*)(vbB + (size_t)x * 32);
        f32x4 e0 = {asf(vv[0] << 16), asf(vv[0] & 0xffff0000u),
                    asf(vv[1] << 16), asf(vv[1] & 0xffff0000u)};
        f32x4 e1 = {asf(vv[2] << 16), asf(vv[2] & 0xffff0000u),
                    asf(vv[3] << 16), asf(vv[3] & 0xffff0000u)};
        sv0 += e0 * pv;
        sv1 += e1 * pv;
      }
      av0 = av0 * r + sv0;
      av1 = av1 * r + sv1;
    }

    // ---- D2: PE via MFMA, both tiles into same C (one rescale) ------------
    {
      f32x4 rgv = *(const f32x4*)(Rg + (hq & 1) * 4);
      const float* pAr = Pf + (lane & 7) * PSTR + (hq & 1) * 8;
      f32x4 pa0 = *(const f32x4*)(pAr);
      f32x4 pa1 = *(const f32x4*)(pAr + 4);
      f32x4 pb0 = *(const f32x4*)(pAr + 16);
      f32x4 pb1 = *(const f32x4*)(pAr + 20);
      u32x4 apkA, apkB;
      apkA[0] = cvtpk(pa0.x, pa0.y); apkA[1] = cvtpk(pa0.z, pa0.w);
      apkA[2] = cvtpk(pa1.x, pa1.y); apkA[3] = cvtpk(pa1.z, pa1.w);
      apkB[0] = cvtpk(pb0.x, pb0.y); apkB[1] = cvtpk(pb0.z, pb0.w);
      apkB[2] = cvtpk(pb1.x, pb1.y); apkB[3] = cvtpk(pb1.z, pb1.w);
      if (hq >= 2) { apkA = (u32x4){0u,0u,0u,0u}; apkB = (u32x4){0u,0u,0u,0u}; }
      short8 pAfA = __builtin_bit_cast(short8, apkA);
      short8 pAfB = __builtin_bit_cast(short8, apkB);
      const float* cbA = tA + (hq & 1) * 8 * TSTR + j16;
      const float* cbB = tB + (hq & 1) * 8 * TSTR + j16;
#define PE_STEP2(ACC, NT) {                                                  \
      float a0_ = cbA[(NT)*16 + 0*TSTR], a1_ = cbA[(NT)*16 + 1*TSTR];        \
      float a2_ = cbA[(NT)*16 + 2*TSTR], a3_ = cbA[(NT)*16 + 3*TSTR];        \
      float a4_ = cbA[(NT)*16 + 4*TSTR], a5_ = cbA[(NT)*16 + 5*TSTR];        \
      float a6_ = cbA[(NT)*16 + 6*TSTR], a7_ = cbA[(NT)*16 + 7*TSTR];        \
      u32x4 bka;                                                             \
      bka[0] = cvtpk(a0_, a1_); bka[1] = cvtpk(a2_, a3_);                    \
      bka[2] = cvtpk(a4_, a5_); bka[3] = cvtpk(a6_, a7_);                    \
      float b0_ = cbB[(NT)*16 + 0*TSTR], b1_ = cbB[(NT)*16 + 1*TSTR];        \
      float b2_ = cbB[(NT)*16 + 2*TSTR], b3_ = cbB[(NT)*16 + 3*TSTR];        \
      float b4_ = cbB[(NT)*16 + 4*TSTR], b5_ = cbB[(NT)*16 + 5*TSTR];        \
      float b6_ = cbB[(NT)*16 + 6*TSTR], b7_ = cbB[(NT)*16 + 7*TSTR];        \
      u32x4 bkb;                                                             \
      bkb[0] = cvtpk(b0_, b1_); bkb[1] = cvtpk(b2_, b3_);                    \
      bkb[2] = cvtpk(b4_, b5_); bkb[3] = cvtpk(b6_, b7_);                    \
      ACC = ACC * rgv;                                                       \
      ACC = __builtin_amdgcn_mfma_f32_16x16x32_bf16(                         \
          pAfA, __builtin_bit_cast(short8, bka), ACC, 0, 0, 0);              \
      ACC = __builtin_amdgcn_mfma_f32_16x16x32_bf16(                         \
          pAfB, __builtin_bit_cast(short8, bkb), ACC, 0, 0, 0); }
      PE_STEP2(acce0, 0)
      PE_STEP2(acce1, 1)
      PE_STEP2(acce2, 2)
      PE_STEP2(acce3, 3)
#undef PE_STEP2
    }

    // ---- stage next pair (after all reads; same-wave DS order) ------------
    if (pf) {
      float* wa = tA + jrl * TSTR + c4 * 16;
      float* wb = tB + jrl * TSTR + c4 * 16;
      *(f32x4*)(wa + 0) = sA0; *(f32x4*)(wa + 4) = sA1;
      *(f32x4*)(wa + 8) = sA2; *(f32x4*)(wa + 12) = sA3;
      *(f32x4*)(wb + 0) = sB0; *(f32x4*)(wb + 4) = sB1;
      *(f32x4*)(wb + 8) = sB2; *(f32x4*)(wb + 12) = sB3;
    }
  }

  // ---- epilogue: flash-merge 4 wave partials (S reused as MRG) ------------
  __syncthreads();
  float* mrg = S + w * 1040;
  if (lane < 32) {
    int h0 = hq * 4;
    if (j16 == 0) {
#pragma unroll
      for (int r = 0; r < 4; ++r) { mrg[h0 + r] = vm[r]; mrg[8 + h0 + r] = vs[r]; }
    }
#pragma unroll
    for (int r = 0; r < 4; ++r) {
      mrg[528 + (h0 + r) * 64 + 0 + j16] = acce0[r];
      mrg[528 + (h0 + r) * 64 + 16 + j16] = acce1[r];
      mrg[528 + (h0 + r) * 64 + 32 + j16] = acce2[r];
      mrg[528 + (h0 + r) * 64 + 48 + j16] = acce3[r];
    }
  }
  *(f32x4*)(mrg + 16 + jh * 256 + hD * 32 + do4 * 8) = av0;
  *(f32x4*)(mrg + 16 + jh * 256 + hD * 32 + do4 * 8 + 4) = av1;
  __syncthreads();
  {
    int h = t >> 5, d = t & 31;
    float mx = fmaxf(fmaxf(S[h], S[1040 + h]), fmaxf(S[2080 + h], S[3120 + h]));
    float ew[4];
    float ssum = 0.f, vsum = 0.f;
#pragma unroll
    for (int ww = 0; ww < 4; ++ww) {
      const float* mw = S + ww * 1040;
      ew[ww] = __expf(mw[h] - mx);
      ssum += mw[8 + h] * ew[ww];
      vsum += (mw[16 + h * 32 + d] + mw[16 + 256 + h * 32 + d]) * ew[ww];
    }
    float inv = 1.f / ssum;
    size_t obase = ((size_t)(b * 1024 + i)) * 768;
    rescat[obase + h * 32 + d] = vsum * inv;
    float e0 = 0.f, e1 = 0.f;
#pragma unroll
    for (int ww = 0; ww < 4; ++ww) {
      const float* mw = S + ww * 1040;
      e0 += mw[528 + h * 64 + d] * ew[ww];
      e1 += mw[528 + h * 64 + 32 + d] * ew[ww];
    }
    rescat[obase + 256 + h * 64 + d] = e0 * inv;
    rescat[obase + 256 + h * 64 + 32 + d] = e1 * inv;
  }
}

// ---------------- kernel C: output projection ----------------------------
__global__ __launch_bounds__(256) void out_proj(
    const float* __restrict__ rescat, const float* __restrict__ Wo,
    const float* __restrict__ bo, float* __restrict__ out) {
  __shared__ __align__(16) float xs[8 * 768];
  int t = threadIdx.x;
  int row0 = blockIdx.x * 8;
#pragma unroll
  for (int p = 0; p < 6; ++p) {
    int f = p * 256 + t;
    *(f32x4*)(&xs[f * 4]) = *(const f32x4*)(rescat + (size_t)row0 * 768 + f * 4);
  }
  __syncthreads();
  float acc[8];
#pragma unroll
  for (int r = 0; r < 8; ++r) acc[r] = 0.f;
  for (int c = 0; c < 768; ++c) {
    float w = Wo[c * 256 + t];
#pragma unroll
    for (int r = 0; r < 8; ++r) acc[r] += xs[r * 768 + c] * w;
  }
  float bias = bo[t];
#pragma unroll
  for (int r = 0; r < 8; ++r)
    out[(size_t)(row0 + r) * 256 + t] = acc[r] + bias;
}

// ---------------- launch ---------------------------------------------------
extern "C" void kernel_launch(void* const* d_in, const int* in_sizes, int n_in,
                              void* d_out, int out_size, void* d_ws, size_t ws_size,
                              hipStream_t stream) {
  const float* node = (const float*)d_in[0];
  const float* edge = (const float*)d_in[1];
  const unsigned char* mask = (const unsigned char*)d_in[2];
  const float* Wq = (const float*)d_in[3];
  const float* Wk = (const float*)d_in[4];
  const float* Wv = (const float*)d_in[5];
  const float* We = (const float*)d_in[6];
  const float* be = (const float*)d_in[7];
  const float* Wo = (const float*)d_in[8];
  const float* bo = (const float*)d_in[9];

  float* ws = (float*)d_ws;
  float* qw = ws;                              // 524288 f32
  u16* kwb = (u16*)(ws + 524288);              // 524288 bf16
  u16* vwb = kwb + 524288;                     // 524288 bf16
  float* rescat = ws + 1048576;                // 1572864 f32
  float* mask_f = ws + 2621440;                // 2048 f32

  hipLaunchKernelGGL(mask_norm, dim3(1), dim3(256), 0, stream, mask, mask_f);
  hipLaunchKernelGGL(qkv_rope, dim3(256), dim3(256), 0, stream,
                     node, Wq, Wk, Wv, qw, kwb, vwb);
  hipLaunchKernelGGL(attn_fused, dim3(2048), dim3(256), 0, stream,
                     edge, qw, kwb, vwb, We, be, mask_f, rescat);
  hipLaunchKernelGGL(out_proj, dim3(256), dim3(256), 0, stream,
                     rescat, Wo, bo, (float*)d_out);
}